// Round 9
// baseline (220.696 us; speedup 1.0000x reference)
//
#include <hip/hip_runtime.h>
#include <hip/hip_bf16.h>

typedef float f32x4 __attribute__((ext_vector_type(4)));
typedef short short8 __attribute__((ext_vector_type(8)));

#define LDH 7168
#define MFMA16(d, x, y) d = __builtin_amdgcn_mfma_f32_16x16x32_bf16(x, y, d, 0, 0, 0)

__device__ __forceinline__ void async_ld16(const void* g, void* l) {
  __builtin_amdgcn_global_load_lds(
      (const __attribute__((address_space(1))) unsigned int*)g,
      (__attribute__((address_space(3))) unsigned int*)l, 16, 0, 0);
}

__device__ __forceinline__ float bf2f(unsigned short u) {
  union { unsigned int i; float f; } c; c.i = ((unsigned int)u) << 16; return c.f;
}

__device__ __forceinline__ ushort4 pack_bf16x4(float4 v) {
  ushort4 u;
  __hip_bfloat16 b;
  b = __float2bfloat16(v.x); u.x = *(unsigned short*)&b;
  b = __float2bfloat16(v.y); u.y = *(unsigned short*)&b;
  b = __float2bfloat16(v.z); u.z = *(unsigned short*)&b;
  b = __float2bfloat16(v.w); u.w = *(unsigned short*)&b;
  return u;
}

// ---------------- decode Win: (7168,1024) bf16 — vectorized
__global__ __launch_bounds__(256) void decode_win_k(const float* __restrict__ cb,
                                                    const int* __restrict__ idx,
                                                    __hip_bfloat16* __restrict__ Win) {
  const int o = blockIdx.x;
  const int cluster = o >> 6;
  const int c = threadIdx.x >> 4;            // 0..15
  const int s4 = (threadIdx.x & 15) * 4;     // 0..60
  const int k0 = idx[o * 16 + c];
  const int k1 = idx[(7168 + o) * 16 + c];
  const float4 v0 = *(const float4*)&cb[((((size_t)cluster) * 16 + c) * 64 + k0) * 64 + s4];
  const float4 v1 = *(const float4*)&cb[((((size_t)(112 + cluster)) * 16 + c) * 64 + k1) * 64 + s4];
  float4 v; v.x = v0.x + v1.x; v.y = v0.y + v1.y; v.z = v0.z + v1.z; v.w = v0.w + v1.w;
  *(ushort4*)&Win[(size_t)o * 1024 + c * 64 + s4] = pack_bf16x4(v);
}

// ---------------- decode Weff: (1024,5120) bf16 — vectorized
__global__ __launch_bounds__(256) void decode_weff_k(const float* __restrict__ cb,
                                                     const int* __restrict__ idx,
                                                     __hip_bfloat16* __restrict__ W) {
  const int o = blockIdx.x;          // 0..1023
  const int cl1 = o >> 7, cl2 = cl1 + 8;
  for (int e4 = threadIdx.x * 4; e4 < 5120; e4 += 1024) {
    const int c = e4 / 320, s = e4 - c * 320;
    float4 acc = {0.f, 0.f, 0.f, 0.f};
    #pragma unroll
    for (int r = 0; r < 2; ++r) {
      const int ka = idx[((size_t)r * 2048 + o) * 16 + c];
      const int kb = idx[((size_t)r * 2048 + o + 1024) * 16 + c];
      const float4 va = *(const float4*)&cb[((((size_t)r * 16 + cl1) * 16 + c) * 64 + ka) * 320 + s];
      const float4 vb = *(const float4*)&cb[((((size_t)r * 16 + cl2) * 16 + c) * 64 + kb) * 320 + s];
      acc.x += va.x + vb.x; acc.y += va.y + vb.y; acc.z += va.z + vb.z; acc.w += va.w + vb.w;
    }
    *(ushort4*)&W[(size_t)o * 5120 + e4] = pack_bf16x4(acc);
  }
}

// ---------------- LayerNorm: x fp32 (4096,1024) -> xn bf16
__global__ __launch_bounds__(256) void ln_k(const float* __restrict__ x,
                                            __hip_bfloat16* __restrict__ xn) {
  const int row = blockIdx.x;
  const float4 v = ((const float4*)(x + (size_t)row * 1024))[threadIdx.x];
  float s = v.x + v.y + v.z + v.w;
  float s2 = v.x * v.x + v.y * v.y + v.z * v.z + v.w * v.w;
  #pragma unroll
  for (int off = 32; off > 0; off >>= 1) {
    s += __shfl_down(s, off, 64);
    s2 += __shfl_down(s2, off, 64);
  }
  __shared__ float red[8];
  if ((threadIdx.x & 63) == 0) { red[threadIdx.x >> 6] = s; red[4 + (threadIdx.x >> 6)] = s2; }
  __syncthreads();
  s = red[0] + red[1] + red[2] + red[3];
  s2 = red[4] + red[5] + red[6] + red[7];
  const float mu = s * (1.f / 1024.f);
  const float rstd = rsqrtf(s2 * (1.f / 1024.f) - mu * mu + 1e-5f);
  float4 nv;
  nv.x = (v.x - mu) * rstd; nv.y = (v.y - mu) * rstd;
  nv.z = (v.z - mu) * rstd; nv.w = (v.w - mu) * rstd;
  *(ushort4*)(xn + (size_t)row * 1024 + threadIdx.x * 4) = pack_bf16x4(nv);
}

// ---------------- GEMM1 (256x256 8-phase, counted-vmcnt half-tile pipeline + 2D-XCD map).
// h[m][o] = sum_c xn[m][c]*Win[o][c]. M=4096, N=7168, K=1024 (16 K-tiles).
// Per tile t group: ph1 stages A-half1(t+1); ph3 B-half0(t+2); ph4 B-half1+A-half0(t+2);
// boundary wait vmcnt(6) (last 3 half-units in flight) — never 0 until tail.
__global__ __launch_bounds__(512, 2) void gemm1_k(const __hip_bfloat16* __restrict__ A,
                                                  const __hip_bfloat16* __restrict__ B,
                                                  __hip_bfloat16* __restrict__ C,
                                                  __hip_bfloat16* __restrict__ vT) {
  __shared__ ushort sm[65536];  // 2 bufs x (A 16384 | B 16384) elems = 128 KiB
  const int tid = threadIdx.x;
  const int lane = tid & 63, wid = tid >> 6;
  const int g = lane >> 4, r16 = lane & 15;
  const int wr = wid >> 2, wc = wid & 3;

  // 2D XCD map: XCD covers 4(M) x 14(N) tile rectangle.
  const int x = blockIdx.x & 7, local = blockIdx.x >> 3;   // 448 blocks
  const int mb = (x >> 1) * 4 + local / 14;
  const int nb = (x & 1) * 14 + local % 14;
  const int m0 = mb * 256, n0 = nb * 256;

  // half-tile stagers: h = row-half (0: rows 0-127, 1: rows 128-255); 2 loads/thread.
  auto stA = [&](int tt, int hf) {
    #pragma unroll
    for (int i = 0; i < 2; ++i) {
      const int c = hf * 1024 + i * 512 + tid;
      const int lc = c ^ (((c >> 5) & 1) << 1);
      const int row = lc >> 3, col = (lc & 7) * 8;
      async_ld16(&A[(size_t)(m0 + row) * 1024 + tt * 64 + col], &sm[(tt & 1) * 32768 + c * 8]);
    }
  };
  auto stB = [&](int tt, int hf) {
    #pragma unroll
    for (int i = 0; i < 2; ++i) {
      const int c = hf * 1024 + i * 512 + tid;
      const int lc = c ^ (((c >> 5) & 1) << 1);
      const int row = lc >> 3, col = (lc & 7) * 8;
      async_ld16(&B[(size_t)(n0 + row) * 1024 + tt * 64 + col], &sm[(tt & 1) * 32768 + 16384 + c * 8]);
    }
  };
  auto rdA = [&](int base, int mm, int kk) -> short8 {
    const int row = wr * 128 + mm * 16 + r16;
    int e = row * 64 + kk * 32 + g * 8;
    e ^= ((row >> 2) & 1) << 4;
    return *(const short8*)&sm[base + e];
  };
  auto rdB = [&](int base, int nn, int kk) -> short8 {
    const int row = wc * 64 + nn * 16 + r16;
    int e = row * 64 + kk * 32 + g * 8;
    e ^= ((row >> 2) & 1) << 4;
    return *(const short8*)&sm[base + 16384 + e];
  };

  f32x4 acc[8][4] = {};

  // prologue: tiles 0 and 1 fully staged; wait for tile 0 (tile 1 stays in flight).
  stA(0, 0); stA(0, 1); stB(0, 0); stB(0, 1);
  stA(1, 0); stA(1, 1); stB(1, 0); stB(1, 1);
  asm volatile("s_waitcnt vmcnt(8)" ::: "memory");
  __builtin_amdgcn_s_barrier();
  __builtin_amdgcn_sched_barrier(0);

  #pragma unroll 2
  for (int t = 0; t < 16; ++t) {
    const int base = (t & 1) * 32768;
    short8 a0[4][2], a1[4][2], b0[2][2], b1[2][2];
    // ph1: reads a0,b0; stage A-half1(t+1) (tile t+1's other units staged 2 groups ago)
    #pragma unroll
    for (int mm = 0; mm < 4; ++mm) { a0[mm][0] = rdA(base, mm, 0); a0[mm][1] = rdA(base, mm, 1); }
    #pragma unroll
    for (int nn = 0; nn < 2; ++nn) { b0[nn][0] = rdB(base, nn, 0); b0[nn][1] = rdB(base, nn, 1); }
    if (t >= 1 && t + 1 < 16) stA(t + 1, 1);
    __builtin_amdgcn_s_setprio(1);
    #pragma unroll
    for (int mm = 0; mm < 4; ++mm)
      #pragma unroll
      for (int nn = 0; nn < 2; ++nn) {
        MFMA16(acc[mm][nn], a0[mm][0], b0[nn][0]);
        MFMA16(acc[mm][nn], a0[mm][1], b0[nn][1]);
      }
    __builtin_amdgcn_s_setprio(0);
    __builtin_amdgcn_s_barrier();
    __builtin_amdgcn_sched_barrier(0);
    // ph2: reads b1; MFMA q01
    #pragma unroll
    for (int nn = 0; nn < 2; ++nn) { b1[nn][0] = rdB(base, 2 + nn, 0); b1[nn][1] = rdB(base, 2 + nn, 1); }
    __builtin_amdgcn_s_setprio(1);
    #pragma unroll
    for (int mm = 0; mm < 4; ++mm)
      #pragma unroll
      for (int nn = 0; nn < 2; ++nn) {
        MFMA16(acc[mm][2 + nn], a0[mm][0], b1[nn][0]);
        MFMA16(acc[mm][2 + nn], a0[mm][1], b1[nn][1]);
      }
    __builtin_amdgcn_s_setprio(0);
    __builtin_amdgcn_s_barrier();
    __builtin_amdgcn_sched_barrier(0);
    // ph3: reads a1; stage B-half0(t+2) (B of tile t fully read after ph2); MFMA q11
    #pragma unroll
    for (int mm = 0; mm < 4; ++mm) { a1[mm][0] = rdA(base, 4 + mm, 0); a1[mm][1] = rdA(base, 4 + mm, 1); }
    if (t + 2 < 16) stB(t + 2, 0);
    __builtin_amdgcn_s_setprio(1);
    #pragma unroll
    for (int mm = 0; mm < 4; ++mm)
      #pragma unroll
      for (int nn = 0; nn < 2; ++nn) {
        MFMA16(acc[4 + mm][2 + nn], a1[mm][0], b1[nn][0]);
        MFMA16(acc[4 + mm][2 + nn], a1[mm][1], b1[nn][1]);
      }
    __builtin_amdgcn_s_setprio(0);
    __builtin_amdgcn_s_barrier();
    __builtin_amdgcn_sched_barrier(0);
    // ph4: stage B-half1(t+2) + A-half0(t+2) (A fully read after ph3); MFMA q10; counted wait
    if (t + 2 < 16) { stB(t + 2, 1); stA(t + 2, 0); }
    __builtin_amdgcn_s_setprio(1);
    #pragma unroll
    for (int mm = 0; mm < 4; ++mm)
      #pragma unroll
      for (int nn = 0; nn < 2; ++nn) {
        MFMA16(acc[4 + mm][nn], a1[mm][0], b0[nn][0]);
        MFMA16(acc[4 + mm][nn], a1[mm][1], b0[nn][1]);
      }
    __builtin_amdgcn_s_setprio(0);
    if (t + 2 < 16) asm volatile("s_waitcnt vmcnt(6)" ::: "memory");
    else            asm volatile("s_waitcnt vmcnt(0)" ::: "memory");
    __builtin_amdgcn_s_barrier();
    __builtin_amdgcn_sched_barrier(0);
  }

  if (n0 < 6144) {
    #pragma unroll
    for (int mm = 0; mm < 8; ++mm)
      #pragma unroll
      for (int nn = 0; nn < 4; ++nn)
        #pragma unroll
        for (int r = 0; r < 4; ++r) {
          const int m = m0 + wr * 128 + mm * 16 + g * 4 + r;
          const int o = n0 + wc * 64 + nn * 16 + r16;
          C[(size_t)m * LDH + o] = __float2bfloat16(acc[mm][nn][r]);
        }
  } else {
    #pragma unroll
    for (int mm = 0; mm < 8; ++mm)
      #pragma unroll
      for (int nn = 0; nn < 4; ++nn)
        #pragma unroll
        for (int r = 0; r < 4; ++r) {
          const int m = m0 + wr * 128 + mm * 16 + g * 4 + r;
          const int o = n0 + wc * 64 + nn * 16 + r16;
          const int b_ = m >> 10;
          vT[((size_t)b_ * 1024 + (o - 6144)) * 1024 + (m & 1023)] = __float2bfloat16(acc[mm][nn][r]);
        }
  }
}

// ---------------- Flash attention: unchanged (proven).
__global__ __launch_bounds__(256) void attn_k(const __hip_bfloat16* __restrict__ h,
                                              const __hip_bfloat16* __restrict__ vT,
                                              __hip_bfloat16* __restrict__ xa) {
  const int qt = blockIdx.x, head = blockIdx.y, b = blockIdx.z;
  const int tid = threadIdx.x;
  const int lane = tid & 63, w = tid >> 6;
  const int g = lane >> 4, r16 = lane & 15;

  __shared__ __align__(16) __hip_bfloat16 Ks[2][64 * 64];
  __shared__ __align__(16) __hip_bfloat16 Vs[2][64 * 64];
  __shared__ __align__(16) __hip_bfloat16 P[4][16][72];

  const __hip_bfloat16* Kg = h + (size_t)(b * 1024) * LDH + 5120 + head * 64;
  const __hip_bfloat16* Vg = vT + ((size_t)b * 1024 + head * 64) * 1024;

  const size_t qrow = (size_t)(b * 1024 + qt * 64 + w * 16 + r16);
  short8 aq0 = *(const short8*)&h[qrow * LDH + 4096 + head * 64 + g * 8];
  short8 aq1 = *(const short8*)&h[qrow * LDH + 4096 + head * 64 + 32 + g * 8];

  auto stage = [&](int buf, int t) {
    #pragma unroll
    for (int i = 0; i < 2; ++i) {
      const int c_lin = i * 256 + tid;
      const int row = c_lin >> 3;
      const int c_log = (c_lin & 7) ^ (row & 7);
      async_ld16(&Kg[(size_t)(t * 64 + row) * LDH + c_log * 8], &Ks[buf][c_lin * 8]);
    }
    #pragma unroll
    for (int i = 0; i < 2; ++i) {
      const int c_lin = i * 256 + tid;
      const int row = c_lin >> 3;
      const int c_log = (c_lin & 7) ^ (row & 7);
      async_ld16(&Vg[(size_t)row * 1024 + t * 64 + c_log * 8], &Vs[buf][c_lin * 8]);
    }
  };

  f32x4 o_acc[4] = {};
  float m_r[4], l_r[4];
  #pragma unroll
  for (int r = 0; r < 4; ++r) { m_r[r] = -1e30f; l_r[r] = 0.f; }

  stage(0, 0);
  for (int t = 0; t < 16; ++t) {
    const int buf = t & 1;
    if (t + 1 < 16) {
      stage(buf ^ 1, t + 1);
      asm volatile("s_waitcnt vmcnt(4)" ::: "memory");
    } else {
      asm volatile("s_waitcnt vmcnt(0)" ::: "memory");
    }
    __builtin_amdgcn_s_barrier();
    __builtin_amdgcn_sched_barrier(0);

    f32x4 s_acc[4] = {};
    #pragma unroll
    for (int nn = 0; nn < 4; ++nn) {
      const int row = nn * 16 + r16;
      short8 bk0 = *(const short8*)&Ks[buf][row * 64 + ((g ^ (row & 7)) * 8)];
      short8 bk1 = *(const short8*)&Ks[buf][row * 64 + (((g + 4) ^ (row & 7)) * 8)];
      s_acc[nn] = __builtin_amdgcn_mfma_f32_16x16x32_bf16(aq0, bk0, s_acc[nn], 0, 0, 0);
      s_acc[nn] = __builtin_amdgcn_mfma_f32_16x16x32_bf16(aq1, bk1, s_acc[nn], 0, 0, 0);
    }
    #pragma unroll
    for (int nn = 0; nn < 4; ++nn) s_acc[nn] *= 0.125f;

    #pragma unroll
    for (int r = 0; r < 4; ++r) {
      float mx = fmaxf(fmaxf(s_acc[0][r], s_acc[1][r]), fmaxf(s_acc[2][r], s_acc[3][r]));
      #pragma unroll
      for (int off = 1; off < 16; off <<= 1) mx = fmaxf(mx, __shfl_xor(mx, off, 64));
      const float mn = fmaxf(m_r[r], mx);
      const float al = __expf(m_r[r] - mn);
      m_r[r] = mn;
      float ps = 0.f;
      #pragma unroll
      for (int nn = 0; nn < 4; ++nn) {
        const float p = __expf(s_acc[nn][r] - mn);
        s_acc[nn][r] = p;
        ps += p;
      }
      #pragma unroll
      for (int off = 1; off < 16; off <<= 1) ps += __shfl_xor(ps, off, 64);
      l_r[r] = l_r[r] * al + ps;
      o_acc[0][r] *= al; o_acc[1][r] *= al; o_acc[2][r] *= al; o_acc[3][r] *= al;
    }

    #pragma unroll
    for (int nn = 0; nn < 4; ++nn)
      #pragma unroll
      for (int r = 0; r < 4; ++r)
        P[w][g * 4 + r][nn * 16 + r16] = __float2bfloat16(s_acc[nn][r]);
    short8 ap0 = *(const short8*)&P[w][r16][g * 8];
    short8 ap1 = *(const short8*)&P[w][r16][32 + g * 8];

    #pragma unroll
    for (int nn = 0; nn < 4; ++nn) {
      const int row = nn * 16 + r16;
      short8 bv0 = *(const short8*)&Vs[buf][row * 64 + ((g ^ (row & 7)) * 8)];
      short8 bv1 = *(const short8*)&Vs[buf][row * 64 + (((g + 4) ^ (row & 7)) * 8)];
      o_acc[nn] = __builtin_amdgcn_mfma_f32_16x16x32_bf16(ap0, bv0, o_acc[nn], 0, 0, 0);
      o_acc[nn] = __builtin_amdgcn_mfma_f32_16x16x32_bf16(ap1, bv1, o_acc[nn], 0, 0, 0);
    }
    __builtin_amdgcn_s_barrier();
    __builtin_amdgcn_sched_barrier(0);
  }

  #pragma unroll
  for (int r = 0; r < 4; ++r) {
    const float inv = 1.0f / l_r[r];
    const size_t mrow = (size_t)(b * 1024 + qt * 64 + w * 16 + g * 4 + r);
    #pragma unroll
    for (int nn = 0; nn < 4; ++nn)
      xa[mrow * 1024 + head * 64 + nn * 16 + r16] = __float2bfloat16(o_acc[nn][r] * inv);
  }
}

// ---------------- GEMM2 (256x256 8-phase counted-vmcnt, split-K 4).
// M=4096, N=1024, K=5120; z covers K-tiles [z*20, z*20+20).
__global__ __launch_bounds__(512, 2) void gemm2_k(const __hip_bfloat16* __restrict__ hbuf,
                                                  const __hip_bfloat16* __restrict__ xa,
                                                  const __hip_bfloat16* __restrict__ W,
                                                  __hip_bfloat16* __restrict__ p0,
                                                  __hip_bfloat16* __restrict__ p1,
                                                  __hip_bfloat16* __restrict__ p2,
                                                  float* __restrict__ out) {
  __shared__ ushort sm[65536];
  const int tid = threadIdx.x;
  const int lane = tid & 63, wid = tid >> 6;
  const int g = lane >> 4, r16 = lane & 15;
  const int wr = wid >> 2, wc = wid & 3;

  int bid = blockIdx.x;                       // 64 tiles
  bid = (bid & 7) * 8 + (bid >> 3);           // XCD-contiguous chunks
  const int mb = bid >> 2, nb = bid & 3;
  const int m0 = mb * 256, n0 = nb * 256;
  const int z = blockIdx.y;
  const int kt0 = z * 20;                     // 20 local K-tiles

  auto stA = [&](int lt, int hf) {
    const int gt = kt0 + lt;
    const __hip_bfloat16* Ab; size_t lda; int kc;
    if (gt < 64) { Ab = hbuf; lda = LDH;  kc = gt * 64; }
    else         { Ab = xa;   lda = 1024; kc = gt * 64 - 4096; }
    #pragma unroll
    for (int i = 0; i < 2; ++i) {
      const int c = hf * 1024 + i * 512 + tid;
      const int lc = c ^ (((c >> 5) & 1) << 1);
      const int row = lc >> 3, col = (lc & 7) * 8;
      async_ld16(&Ab[(size_t)(m0 + row) * lda + kc + col], &sm[(lt & 1) * 32768 + c * 8]);
    }
  };
  auto stB = [&](int lt, int hf) {
    const int gt = kt0 + lt;
    #pragma unroll
    for (int i = 0; i < 2; ++i) {
      const int c = hf * 1024 + i * 512 + tid;
      const int lc = c ^ (((c >> 5) & 1) << 1);
      const int row = lc >> 3, col = (lc & 7) * 8;
      async_ld16(&W[(size_t)(n0 + row) * 5120 + gt * 64 + col], &sm[(lt & 1) * 32768 + 16384 + c * 8]);
    }
  };
  auto rdA = [&](int base, int mm, int kk) -> short8 {
    const int row = wr * 128 + mm * 16 + r16;
    int e = row * 64 + kk * 32 + g * 8;
    e ^= ((row >> 2) & 1) << 4;
    return *(const short8*)&sm[base + e];
  };
  auto rdB = [&](int base, int nn, int kk) -> short8 {
    const int row = wc * 64 + nn * 16 + r16;
    int e = row * 64 + kk * 32 + g * 8;
    e ^= ((row >> 2) & 1) << 4;
    return *(const short8*)&sm[base + 16384 + e];
  };

  f32x4 acc[8][4] = {};

  stA(0, 0); stA(0, 1); stB(0, 0); stB(0, 1);
  stA(1, 0); stA(1, 1); stB(1, 0); stB(1, 1);
  asm volatile("s_waitcnt vmcnt(8)" ::: "memory");
  __builtin_amdgcn_s_barrier();
  __builtin_amdgcn_sched_barrier(0);

  #pragma unroll 2
  for (int t = 0; t < 20; ++t) {
    const int base = (t & 1) * 32768;
    short8 a0[4][2], a1[4][2], b0[2][2], b1[2][2];
    // ph1
    #pragma unroll
    for (int mm = 0; mm < 4; ++mm) { a0[mm][0] = rdA(base, mm, 0); a0[mm][1] = rdA(base, mm, 1); }
    #pragma unroll
    for (int nn = 0; nn < 2; ++nn) { b0[nn][0] = rdB(base, nn, 0); b0[nn][1] = rdB(base, nn, 1); }
    if (t >= 1 && t + 1 < 20) stA(t + 1, 1);
    __builtin_amdgcn_s_setprio(1);
    #pragma unroll
    for (int mm = 0; mm < 4; ++mm)
      #pragma unroll
      for (int nn = 0; nn < 2; ++nn) {
        MFMA16(acc[mm][nn], a0[mm][0], b0[nn][0]);
        MFMA16(acc[mm][nn], a0[mm][1], b0[nn][1]);
      }
    __builtin_amdgcn_s_setprio(0);
    __builtin_amdgcn_s_barrier();
    __builtin_amdgcn_sched_barrier(0);
    // ph2
    #pragma unroll
    for (int nn = 0; nn < 2; ++nn) { b1[nn][0] = rdB(base, 2 + nn, 0); b1[nn][1] = rdB(base, 2 + nn, 1); }
    __builtin_amdgcn_s_setprio(1);
    #pragma unroll
    for (int mm = 0; mm < 4; ++mm)
      #pragma unroll
      for (int nn = 0; nn < 2; ++nn) {
        MFMA16(acc[mm][2 + nn], a0[mm][0], b1[nn][0]);
        MFMA16(acc[mm][2 + nn], a0[mm][1], b1[nn][1]);
      }
    __builtin_amdgcn_s_setprio(0);
    __builtin_amdgcn_s_barrier();
    __builtin_amdgcn_sched_barrier(0);
    // ph3
    #pragma unroll
    for (int mm = 0; mm < 4; ++mm) { a1[mm][0] = rdA(base, 4 + mm, 0); a1[mm][1] = rdA(base, 4 + mm, 1); }
    if (t + 2 < 20) stB(t + 2, 0);
    __builtin_amdgcn_s_setprio(1);
    #pragma unroll
    for (int mm = 0; mm < 4; ++mm)
      #pragma unroll
      for (int nn = 0; nn < 2; ++nn) {
        MFMA16(acc[4 + mm][2 + nn], a1[mm][0], b1[nn][0]);
        MFMA16(acc[4 + mm][2 + nn], a1[mm][1], b1[nn][1]);
      }
    __builtin_amdgcn_s_setprio(0);
    __builtin_amdgcn_s_barrier();
    __builtin_amdgcn_sched_barrier(0);
    // ph4
    if (t + 2 < 20) { stB(t + 2, 1); stA(t + 2, 0); }
    __builtin_amdgcn_s_setprio(1);
    #pragma unroll
    for (int mm = 0; mm < 4; ++mm)
      #pragma unroll
      for (int nn = 0; nn < 2; ++nn) {
        MFMA16(acc[4 + mm][nn], a1[mm][0], b0[nn][0]);
        MFMA16(acc[4 + mm][nn], a1[mm][1], b0[nn][1]);
      }
    __builtin_amdgcn_s_setprio(0);
    if (t + 2 < 20) asm volatile("s_waitcnt vmcnt(6)" ::: "memory");
    else            asm volatile("s_waitcnt vmcnt(0)" ::: "memory");
    __builtin_amdgcn_s_barrier();
    __builtin_amdgcn_sched_barrier(0);
  }

  __hip_bfloat16* pz = (z == 0) ? p0 : (z == 1) ? p1 : p2;
  #pragma unroll
  for (int mm = 0; mm < 8; ++mm)
    #pragma unroll
    for (int nn = 0; nn < 4; ++nn)
      #pragma unroll
      for (int r = 0; r < 4; ++r) {
        const int m = m0 + wr * 128 + mm * 16 + g * 4 + r;
        const int n = n0 + wc * 64 + nn * 16 + r16;
        if (z == 3) out[(size_t)m * 1024 + n] = acc[mm][nn][r];
        else        pz[(size_t)m * 1024 + n] = __float2bfloat16(acc[mm][nn][r]);
      }
}

// ---------------- reduce: out = out + p0 + p1 + p2 + res
__global__ __launch_bounds__(256) void reduce_k(const __hip_bfloat16* __restrict__ p0,
                                                const __hip_bfloat16* __restrict__ p1,
                                                const __hip_bfloat16* __restrict__ p2,
                                                const float* __restrict__ res,
                                                float* __restrict__ out) {
  const size_t i4 = (size_t)blockIdx.x * 256 + threadIdx.x;
  float4 o = ((const float4*)out)[i4];
  const float4 rr = ((const float4*)res)[i4];
  const ushort4 a0 = ((const ushort4*)p0)[i4];
  const ushort4 a1 = ((const ushort4*)p1)[i4];
  const ushort4 a2 = ((const ushort4*)p2)[i4];
  o.x += rr.x + bf2f(a0.x) + bf2f(a1.x) + bf2f(a2.x);
  o.y += rr.y + bf2f(a0.y) + bf2f(a1.y) + bf2f(a2.y);
  o.z += rr.z + bf2f(a0.z) + bf2f(a1.z) + bf2f(a2.z);
  o.w += rr.w + bf2f(a0.w) + bf2f(a1.w) + bf2f(a2.w);
  ((float4*)out)[i4] = o;
}

extern "C" void kernel_launch(void* const* d_in, const int* in_sizes, int n_in,
                              void* d_out, int out_size, void* d_ws, size_t ws_size,
                              hipStream_t stream) {
  (void)in_sizes; (void)n_in; (void)out_size; (void)ws_size;
  const float* x      = (const float*)d_in[0];
  const float* in_cb  = (const float*)d_in[1];
  const int*   in_idx = (const int*)d_in[2];
  const float* out_cb = (const float*)d_in[3];
  const int*   out_idx= (const int*)d_in[4];
  float* out = (float*)d_out;
  char* ws = (char*)d_ws;

  __hip_bfloat16* Win  = (__hip_bfloat16*)(ws);                 // 14,680,064
  __hip_bfloat16* Weff = (__hip_bfloat16*)(ws + 14680064);      // 10,485,760
  __hip_bfloat16* xn   = (__hip_bfloat16*)(ws + 25165824);      //  8,388,608
  __hip_bfloat16* h    = (__hip_bfloat16*)(ws + 33554432);      // 58,720,256
  __hip_bfloat16* vT   = (__hip_bfloat16*)(ws + 92274688);      //  8,388,608
  __hip_bfloat16* xa   = (__hip_bfloat16*)(ws + 100663296);     //  8,388,608

  __hip_bfloat16* pk0 = Win;   // dead after gemm1
  __hip_bfloat16* pk1 = xn;    // dead after gemm1
  __hip_bfloat16* pk2 = vT;    // dead after attn

  decode_win_k<<<dim3(7168), dim3(256), 0, stream>>>(in_cb, in_idx, Win);
  decode_weff_k<<<dim3(1024), dim3(256), 0, stream>>>(out_cb, out_idx, Weff);
  ln_k<<<dim3(4096), dim3(256), 0, stream>>>(x, xn);
  gemm1_k<<<dim3(448), dim3(512), 0, stream>>>(xn, Win, h, vT);
  attn_k<<<dim3(16, 16, 4), dim3(256), 0, stream>>>(h, vT, xa);
  gemm2_k<<<dim3(64, 4), dim3(512), 0, stream>>>(h, xa, Weff, pk0, pk1, pk2, out);
  reduce_k<<<dim3(4096), dim3(256), 0, stream>>>(pk0, pk1, pk2, x, out);
}